// Round 7
// baseline (731.508 us; speedup 1.0000x reference)
//
#include <hip/hip_runtime.h>
#include <stdint.h>

#define B_  16
#define QL  2048
#define KL  2048
#define FD  128
#define BQ  64
#define BK  32
#define NSTEP (KL/BK)

#define KSTR  136      // K-tile row stride (shorts); b128 reads 2-way (free)
#define VTOFF 4352     // 32*136 shorts; V^T region base
#define BUFS  8448     // 4352 + 128*32 shorts per buffer
#define PSTR  40       // P/T LDS row stride (shorts)
#define MSTR  36       // mask LDS row stride (bytes)

typedef __attribute__((ext_vector_type(8))) short bf16x8;
typedef __attribute__((ext_vector_type(4))) float f32x4;
typedef __attribute__((ext_vector_type(4))) int   i32x4;

__device__ __forceinline__ unsigned short f2b(float f) {
  union { float f; unsigned u; } x; x.f = f;
  return (unsigned short)((x.u + 0x8000u) >> 16);
}

// out = (sum_k !attn*e^s*V)/l - sum_k !attn*!alibi*d*bscale*V,  l = sum_k e^s
// 64 q-rows/block, 4 waves. BK=32 steps, dbuf LDS, 1 barrier/step.
// Masks: cooperative i32x4 nontemporal stream -> byte-packed LDS (am | al<<1).
// V^T: swizzled granule layout, ds_write_b64/ds_read_b64 at LDS minimum.
__global__ __launch_bounds__(256, 2) void alibi_attn(
    const float* __restrict__ qp,
    const float* __restrict__ kp,
    const float* __restrict__ vp,
    const float* __restrict__ cqp,
    const float* __restrict__ ckp,
    const int* __restrict__ amp,
    const int* __restrict__ almp,
    const float* __restrict__ bsp,
    const float* __restrict__ rmp,
    float* __restrict__ outp)
{
  __shared__ unsigned short kv[2 * BUFS];            // 33 KB K + V^T dbuf
  __shared__ unsigned short plds[4][2][16 * PSTR];   // 10 KB wave-private P/T
  __shared__ unsigned char  mlds[2][64 * MSTR];      // 4.5 KB packed masks dbuf

  const int t    = threadIdx.x;
  const int w    = t >> 6;
  const int lane = t & 63;
  const int l15  = lane & 15;
  const int q4   = lane >> 4;

  const int bid  = blockIdx.x;
  const int xcd  = bid & 7, slot = bid >> 3;
  const int b    = (xcd << 1) | (slot >> 5);
  const int qbase = (slot & 31) * BQ;

  const float bscale = bsp[0] / rmp[0];
  const float sl2 = 0.08838834764831845f * 1.44269504089f;  // scale*log2(e)

  // K staging map
  const int kr_st = t >> 3, fb_st = (t & 7) * 4;
  // V staging map: thread owns k-rows 4*vrq..+3, f cols vfc+32d
  const int vrq = t >> 5, vfc = t & 31;
  const int vwp = ((vrq ^ ((vfc >> 1) & 7)) * 4);          // swizzled granule pos
  const int vwa = VTOFF + vfc * 32 + vwp;                  // +1024*d per f-step
  // mask staging map: row t>>2, int cols (t&3)*8..+7
  const int mrow = t >> 2, mcol = (t & 3) * 8;
  const long long mgbase = ((long long)(b * QL + qbase + mrow)) * KL + mcol;
  const int mlo = mrow * MSTR + mcol;
  // PV V^T read offsets (swizzle: s = l15>>1, n-independent)
  const int sv_r = l15 >> 1;
  const int voff0 = ((2 * q4) ^ sv_r) * 4;
  const int voff1 = ((2 * q4 + 1) ^ sv_r) * 4;
  const int vrb = VTOFF + l15 * 32;                        // +512*n per f-tile

  // ---- prologue: Q tile -> LDS bf16 (stride KSTR), read A-frags + coords_q ----
  {
    const float* qg = qp + ((long long)(b * QL + qbase)) * FD;
    #pragma unroll
    for (int i = 0; i < 8; ++i) {
      int idx = t + 256 * i;
      float4 u = ((const float4*)qg)[idx];
      int row = idx >> 5, col = (idx & 31) * 4;
      ushort4 s4; s4.x = f2b(u.x); s4.y = f2b(u.y); s4.z = f2b(u.z); s4.w = f2b(u.w);
      *(ushort4*)&kv[row * KSTR + col] = s4;
    }
  }
  __syncthreads();
  bf16x8 qfrag[4];
  {
    const int m = w * 16 + l15;
    #pragma unroll
    for (int fs = 0; fs < 4; ++fs)
      qfrag[fs] = *(const bf16x8*)&kv[m * KSTR + fs * 32 + q4 * 8];
  }
  float cqx[4], cqy[4];
  #pragma unroll
  for (int r = 0; r < 4; ++r) {
    const int qg_ = qbase + w * 16 + q4 * 4 + r;
    float2 c2 = *(const float2*)(cqp + ((long long)(b * QL + qg_)) * 2);
    cqx[r] = c2.x; cqy[r] = c2.y;
  }
  __syncthreads();   // Q-frag reads done before buf0 is overwritten

  const float* kgb = kp + ((long long)b * KL) * FD;
  const float* vgb = vp + ((long long)b * KL) * FD;

  float ckx_b[2][2], cky_b[2][2];

  // ---- stage tile 0 (K, V^T, masks, coords) into buf0 ----
  {
    i32x4 a0 = __builtin_nontemporal_load((const i32x4*)(amp + mgbase));
    i32x4 a1 = __builtin_nontemporal_load((const i32x4*)(amp + mgbase + 4));
    i32x4 g0 = __builtin_nontemporal_load((const i32x4*)(almp + mgbase));
    i32x4 g1 = __builtin_nontemporal_load((const i32x4*)(almp + mgbase + 4));
    float4 kld[4];
    float  vsc[4][4];
    #pragma unroll
    for (int i = 0; i < 4; ++i)
      kld[i] = *(const float4*)(kgb + (long long)kr_st * FD + fb_st + 32 * i);
    #pragma unroll
    for (int d = 0; d < 4; ++d)
      #pragma unroll
      for (int kk = 0; kk < 4; ++kk)
        vsc[d][kk] = vgb[(long long)(4 * vrq + kk) * FD + vfc + 32 * d];
    #pragma unroll
    for (int s = 0; s < 2; ++s) {
      float2 c2 = *(const float2*)(ckp + ((long long)(b * KL + s * 16 + l15)) * 2);
      ckx_b[0][s] = c2.x; cky_b[0][s] = c2.y;
    }
    unsigned ua = (unsigned)(a0[0] | (a0[1] << 8) | (a0[2] << 16) | (a0[3] << 24));
    unsigned ul = (unsigned)(g0[0] | (g0[1] << 8) | (g0[2] << 16) | (g0[3] << 24));
    *(unsigned*)&mlds[0][mlo] = ua | (ul << 1);
    ua = (unsigned)(a1[0] | (a1[1] << 8) | (a1[2] << 16) | (a1[3] << 24));
    ul = (unsigned)(g1[0] | (g1[1] << 8) | (g1[2] << 16) | (g1[3] << 24));
    *(unsigned*)&mlds[0][mlo + 4] = ua | (ul << 1);
    #pragma unroll
    for (int i = 0; i < 4; ++i) {
      ushort4 s4; s4.x = f2b(kld[i].x); s4.y = f2b(kld[i].y);
      s4.z = f2b(kld[i].z); s4.w = f2b(kld[i].w);
      *(ushort4*)&kv[kr_st * KSTR + fb_st + 32 * i] = s4;
    }
    #pragma unroll
    for (int d = 0; d < 4; ++d) {
      short4 w4;
      w4.x = (short)f2b(vsc[d][0]); w4.y = (short)f2b(vsc[d][1]);
      w4.z = (short)f2b(vsc[d][2]); w4.w = (short)f2b(vsc[d][3]);
      *(short4*)&kv[vwa + 1024 * d] = w4;
    }
  }
  __syncthreads();

  f32x4 O1[8], O2[8];
  #pragma unroll
  for (int n = 0; n < 8; ++n) {
    O1[n] = (f32x4){0.f, 0.f, 0.f, 0.f};
    O2[n] = (f32x4){0.f, 0.f, 0.f, 0.f};
  }
  float lsum[4] = {0.f, 0.f, 0.f, 0.f};

  #pragma unroll 2
  for (int kt = 0; kt < NSTEP; ++kt) {
    const int cur = kt & 1, nxt = cur ^ 1;
    const unsigned short* kb = kv + cur * BUFS;
    unsigned short*       nb = kv + nxt * BUFS;
    const int ktp = (kt + 1 < NSTEP) ? (kt + 1) : kt;
    const int k0p = ktp * BK;

    // ---- prefetch next step (masks first: longest latency) ----
    i32x4 a0 = __builtin_nontemporal_load((const i32x4*)(amp + mgbase + k0p));
    i32x4 a1 = __builtin_nontemporal_load((const i32x4*)(amp + mgbase + k0p + 4));
    i32x4 g0 = __builtin_nontemporal_load((const i32x4*)(almp + mgbase + k0p));
    i32x4 g1 = __builtin_nontemporal_load((const i32x4*)(almp + mgbase + k0p + 4));
    float4 kld[4];
    float  vsc[4][4];
    #pragma unroll
    for (int i = 0; i < 4; ++i)
      kld[i] = *(const float4*)(kgb + (long long)(k0p + kr_st) * FD + fb_st + 32 * i);
    #pragma unroll
    for (int d = 0; d < 4; ++d)
      #pragma unroll
      for (int kk = 0; kk < 4; ++kk)
        vsc[d][kk] = vgb[(long long)(k0p + 4 * vrq + kk) * FD + vfc + 32 * d];
    #pragma unroll
    for (int s = 0; s < 2; ++s) {
      float2 c2 = *(const float2*)(ckp + ((long long)(b * KL + k0p + s * 16 + l15)) * 2);
      ckx_b[nxt][s] = c2.x; cky_b[nxt][s] = c2.y;
    }

    // ---- QK^T over F=128 ----
    f32x4 S0 = (f32x4){0.f, 0.f, 0.f, 0.f};
    f32x4 S1 = (f32x4){0.f, 0.f, 0.f, 0.f};
    #pragma unroll
    for (int fs = 0; fs < 4; ++fs) {
      bf16x8 kb0 = *(const bf16x8*)&kb[(l15)      * KSTR + fs * 32 + q4 * 8];
      bf16x8 kb1 = *(const bf16x8*)&kb[(16 + l15) * KSTR + fs * 32 + q4 * 8];
      S0 = __builtin_amdgcn_mfma_f32_16x16x32_bf16(qfrag[fs], kb0, S0, 0, 0, 0);
      S1 = __builtin_amdgcn_mfma_f32_16x16x32_bf16(qfrag[fs], kb1, S1, 0, 0, 0);
    }

    // ---- transform: masks from packed LDS bytes ----
    #pragma unroll
    for (int s = 0; s < 2; ++s) {
      const f32x4 Sv = s ? S1 : S0;
      #pragma unroll
      for (int r = 0; r < 4; ++r) {
        unsigned char m = mlds[cur][(w * 16 + q4 * 4 + r) * MSTR + s * 16 + l15];
        float e = __builtin_amdgcn_exp2f(Sv[r] * sl2);
        lsum[r] += e;
        float dx = cqx[r] - ckx_b[cur][s], dy = cqy[r] - cky_b[cur][s];
        float d  = sqrtf(fmaf(dx, dx, dy * dy)) * bscale;
        float wv = (m & 1) ? 0.f : e;
        float tv = m ? 0.f : d;
        const int mm = q4 * 4 + r, c = s * 16 + l15;
        plds[w][0][mm * PSTR + c] = f2b(wv);
        plds[w][1][mm * PSTR + c] = f2b(tv);
      }
    }

    // ---- PV: swizzled V^T b64 reads (LDS-minimum, conflict-free) ----
    bf16x8 aw = *(const bf16x8*)&plds[w][0][l15 * PSTR + q4 * 8];
    bf16x8 at = *(const bf16x8*)&plds[w][1][l15 * PSTR + q4 * 8];
    #pragma unroll
    for (int n = 0; n < 8; ++n) {
      short4 v0 = *(const short4*)&kb[vrb + 512 * n + voff0];
      short4 v1 = *(const short4*)&kb[vrb + 512 * n + voff1];
      bf16x8 vb;
      vb[0] = v0.x; vb[1] = v0.y; vb[2] = v0.z; vb[3] = v0.w;
      vb[4] = v1.x; vb[5] = v1.y; vb[6] = v1.z; vb[7] = v1.w;
      O1[n] = __builtin_amdgcn_mfma_f32_16x16x32_bf16(aw, vb, O1[n], 0, 0, 0);
      O2[n] = __builtin_amdgcn_mfma_f32_16x16x32_bf16(at, vb, O2[n], 0, 0, 0);
    }

    // ---- stage next tile into nxt buffers, single barrier ----
    unsigned ua = (unsigned)(a0[0] | (a0[1] << 8) | (a0[2] << 16) | (a0[3] << 24));
    unsigned ul = (unsigned)(g0[0] | (g0[1] << 8) | (g0[2] << 16) | (g0[3] << 24));
    *(unsigned*)&mlds[nxt][mlo] = ua | (ul << 1);
    ua = (unsigned)(a1[0] | (a1[1] << 8) | (a1[2] << 16) | (a1[3] << 24));
    ul = (unsigned)(g1[0] | (g1[1] << 8) | (g1[2] << 16) | (g1[3] << 24));
    *(unsigned*)&mlds[nxt][mlo + 4] = ua | (ul << 1);
    #pragma unroll
    for (int i = 0; i < 4; ++i) {
      ushort4 s4; s4.x = f2b(kld[i].x); s4.y = f2b(kld[i].y);
      s4.z = f2b(kld[i].z); s4.w = f2b(kld[i].w);
      *(ushort4*)&nb[kr_st * KSTR + fb_st + 32 * i] = s4;
    }
    #pragma unroll
    for (int d = 0; d < 4; ++d) {
      short4 w4;
      w4.x = (short)f2b(vsc[d][0]); w4.y = (short)f2b(vsc[d][1]);
      w4.z = (short)f2b(vsc[d][2]); w4.w = (short)f2b(vsc[d][3]);
      *(short4*)&nb[vwa + 1024 * d] = w4;
    }
    __syncthreads();
  }

  // ---- epilogue ----
  #pragma unroll
  for (int off = 1; off < 16; off <<= 1) {
    #pragma unroll
    for (int r = 0; r < 4; ++r) lsum[r] += __shfl_xor(lsum[r], off, 64);
  }
  float linv[4];
  #pragma unroll
  for (int r = 0; r < 4; ++r) linv[r] = 1.0f / lsum[r];

  #pragma unroll
  for (int n = 0; n < 8; ++n) {
    #pragma unroll
    for (int r = 0; r < 4; ++r) {
      const int qg_ = qbase + w * 16 + q4 * 4 + r;
      const int f   = n * 16 + l15;
      float val = O1[n][r] * linv[r] - O2[n][r];
      __builtin_nontemporal_store(val, outp + ((long long)(b * QL + qg_)) * FD + f);
    }
  }
}

extern "C" void kernel_launch(void* const* d_in, const int* in_sizes, int n_in,
                              void* d_out, int out_size, void* d_ws, size_t ws_size,
                              hipStream_t stream) {
  const float* q   = (const float*)d_in[0];
  const float* k   = (const float*)d_in[1];
  const float* v   = (const float*)d_in[2];
  const float* cq  = (const float*)d_in[3];
  const float* ck  = (const float*)d_in[4];
  const int*   am  = (const int*)d_in[5];
  const int*   alm = (const int*)d_in[6];
  const float* bs  = (const float*)d_in[7];
  const float* rm  = (const float*)d_in[8];
  float*       out = (float*)d_out;

  dim3 grid(B_ * (QL / BQ));   // 512 blocks, 2/CU
  dim3 block(256);
  hipLaunchKernelGGL(alibi_attn, grid, block, 0, stream,
                     q, k, v, cq, ck, am, alm, bs, rm, out);
}

// Round 8
// 665.317 us; speedup vs baseline: 1.0995x; 1.0995x over previous
//
#include <hip/hip_runtime.h>
#include <stdint.h>

#define B_  16
#define QL  2048
#define KL  2048
#define FD  128
#define BQ  64
#define BK  32
#define NSTEP (KL/BK)

#define KSTR  136        // K-tile LDS row stride (shorts)
#define VTOFF 4352       // 32*136
#define VTSTR 36         // V^T LDS row stride (shorts); b128 reads conflict-free
#define BUFS  8960       // 4352 + 128*36
#define PSTR  40
#define MSTR  36
#define WS_HALF (B_*KL*FD)   // shorts per converted array (8 MB)

typedef __attribute__((ext_vector_type(8))) short bf16x8;
typedef __attribute__((ext_vector_type(4))) float f32x4;
typedef __attribute__((ext_vector_type(4))) int   i32x4;

__device__ __forceinline__ unsigned short f2b(float f) {
  union { float f; unsigned u; } x; x.f = f;
  return (unsigned short)((x.u + 0x8000u) >> 16);
}

// ---- pre-pass 1: K fp32 -> bf16, same layout ----
__global__ __launch_bounds__(256) void conv_k(const float* __restrict__ kp,
                                              unsigned short* __restrict__ kb) {
  int idx = (blockIdx.x * 256 + threadIdx.x) * 4;
  float4 u = *(const float4*)(kp + idx);
  ushort4 s4; s4.x = f2b(u.x); s4.y = f2b(u.y); s4.z = f2b(u.z); s4.w = f2b(u.w);
  *(ushort4*)(kb + idx) = s4;
}

// ---- pre-pass 2: V fp32 [b][k][f] -> bf16 tiled-transposed [b][kt][f][32] ----
__global__ __launch_bounds__(256) void conv_vt(const float* __restrict__ vp,
                                               unsigned short* __restrict__ vt) {
  __shared__ float tl[32 * 132];
  const int t = threadIdx.x, b = blockIdx.x >> 6, kt = blockIdx.x & 63;
  const int r = t >> 3, f0 = (t & 7) * 16;
  const float* src = vp + ((long long)(b * KL + kt * 32 + r)) * FD + f0;
  #pragma unroll
  for (int i = 0; i < 4; ++i)
    *(float4*)&tl[r * 132 + f0 + 4 * i] = *(const float4*)(src + 4 * i);
  __syncthreads();
  const int f = t >> 1, half = t & 1;
  bf16x8 o0, o1;
  #pragma unroll
  for (int j = 0; j < 8; ++j)  o0[j] = (short)f2b(tl[(half * 16 + j) * 132 + f]);
  #pragma unroll
  for (int j = 0; j < 8; ++j)  o1[j] = (short)f2b(tl[(half * 16 + 8 + j) * 132 + f]);
  unsigned short* dst = vt + ((long long)((b * 64 + kt) * FD + f)) * 32 + half * 16;
  *(bf16x8*)dst = o0;
  *(bf16x8*)(dst + 8) = o1;
}

// out = (sum_k !attn*e^s*V)/l - sum_k !attn*!alibi*d*bscale*V,  l = sum_k e^s
// K/V staged from L2-resident bf16 workspace; masks are the only HBM stream.
__global__ __launch_bounds__(256, 2) void alibi_attn(
    const unsigned short* __restrict__ kbp,   // bf16 K [b][k][f]
    const unsigned short* __restrict__ vtp,   // bf16 V^T tiles [b][kt][f][32]
    const float* __restrict__ qp,
    const float* __restrict__ cqp,
    const float* __restrict__ ckp,
    const int* __restrict__ amp,
    const int* __restrict__ almp,
    const float* __restrict__ bsp,
    const float* __restrict__ rmp,
    float* __restrict__ outp)
{
  __shared__ unsigned short kv[2 * BUFS];            // 35 KB K + V^T dbuf
  __shared__ unsigned short plds[4][2][16 * PSTR];   // 10 KB wave-private P/T
  __shared__ unsigned char  mlds[2][64 * MSTR];      // 4.5 KB packed masks dbuf

  const int t    = threadIdx.x;
  const int w    = t >> 6;
  const int lane = t & 63;
  const int l15  = lane & 15;
  const int q4   = lane >> 4;

  const int bid  = blockIdx.x;
  const int xcd  = bid & 7, slot = bid >> 3;
  const int b    = (xcd << 1) | (slot >> 5);
  const int qbase = (slot & 31) * BQ;

  const float bscale = bsp[0] / rmp[0];
  const float sl2 = 0.08838834764831845f * 1.44269504089f;  // scale*log2(e)

  // K staging: thread row t>>3, 16 shorts at col (t&7)*16
  const int kr_st = t >> 3, kc_st = (t & 7) * 16;
  // V staging: 16 contiguous shorts at t*16 within the 8 KB tile
  const int vf_st = t >> 1, vh_st = (t & 1) * 16;
  // mask staging
  const int mrow = t >> 2, mcol = (t & 3) * 8;
  const long long mgbase = ((long long)(b * QL + qbase + mrow)) * KL + mcol;
  const int mlo = mrow * MSTR + mcol;

  // ---- prologue: Q tile -> LDS bf16, read A-frags + coords_q ----
  {
    const float* qg = qp + ((long long)(b * QL + qbase)) * FD;
    #pragma unroll
    for (int i = 0; i < 8; ++i) {
      int idx = t + 256 * i;
      float4 u = ((const float4*)qg)[idx];
      int row = idx >> 5, col = (idx & 31) * 4;
      ushort4 s4; s4.x = f2b(u.x); s4.y = f2b(u.y); s4.z = f2b(u.z); s4.w = f2b(u.w);
      *(ushort4*)&kv[row * KSTR + col] = s4;
    }
  }
  __syncthreads();
  bf16x8 qfrag[4];
  {
    const int m = w * 16 + l15;
    #pragma unroll
    for (int fs = 0; fs < 4; ++fs)
      qfrag[fs] = *(const bf16x8*)&kv[m * KSTR + fs * 32 + q4 * 8];
  }
  float cqx[4], cqy[4];
  #pragma unroll
  for (int r = 0; r < 4; ++r) {
    const int qg_ = qbase + w * 16 + q4 * 4 + r;
    float2 c2 = *(const float2*)(cqp + ((long long)(b * QL + qg_)) * 2);
    cqx[r] = c2.x; cqy[r] = c2.y;
  }
  __syncthreads();

  const unsigned short* kgb = kbp + (long long)b * KL * FD;
  const unsigned short* vgb = vtp + (long long)b * KL * FD;

  float ckx_b[2][2], cky_b[2][2];

  // ---- stage tile 0 ----
  {
    i32x4 a0 = __builtin_nontemporal_load((const i32x4*)(amp + mgbase));
    i32x4 a1 = __builtin_nontemporal_load((const i32x4*)(amp + mgbase + 4));
    i32x4 g0 = __builtin_nontemporal_load((const i32x4*)(almp + mgbase));
    i32x4 g1 = __builtin_nontemporal_load((const i32x4*)(almp + mgbase + 4));
    bf16x8 k0l = *(const bf16x8*)(kgb + kr_st * FD + kc_st);
    bf16x8 k1l = *(const bf16x8*)(kgb + kr_st * FD + kc_st + 8);
    bf16x8 v0l = *(const bf16x8*)(vgb + t * 16);
    bf16x8 v1l = *(const bf16x8*)(vgb + t * 16 + 8);
    #pragma unroll
    for (int s = 0; s < 2; ++s) {
      float2 c2 = *(const float2*)(ckp + ((long long)(b * KL + s * 16 + l15)) * 2);
      ckx_b[0][s] = c2.x; cky_b[0][s] = c2.y;
    }
    unsigned ua = (unsigned)(a0[0] | (a0[1] << 8) | (a0[2] << 16) | (a0[3] << 24));
    unsigned ul = (unsigned)(g0[0] | (g0[1] << 8) | (g0[2] << 16) | (g0[3] << 24));
    *(unsigned*)&mlds[0][mlo] = ua | (ul << 1);
    ua = (unsigned)(a1[0] | (a1[1] << 8) | (a1[2] << 16) | (a1[3] << 24));
    ul = (unsigned)(g1[0] | (g1[1] << 8) | (g1[2] << 16) | (g1[3] << 24));
    *(unsigned*)&mlds[0][mlo + 4] = ua | (ul << 1);
    *(bf16x8*)&kv[kr_st * KSTR + kc_st]     = k0l;
    *(bf16x8*)&kv[kr_st * KSTR + kc_st + 8] = k1l;
    *(bf16x8*)&kv[VTOFF + vf_st * VTSTR + vh_st]     = v0l;
    *(bf16x8*)&kv[VTOFF + vf_st * VTSTR + vh_st + 8] = v1l;
  }
  __syncthreads();

  f32x4 O1[8], O2[8];
  #pragma unroll
  for (int n = 0; n < 8; ++n) {
    O1[n] = (f32x4){0.f, 0.f, 0.f, 0.f};
    O2[n] = (f32x4){0.f, 0.f, 0.f, 0.f};
  }
  float lsum[4] = {0.f, 0.f, 0.f, 0.f};

  #pragma unroll 2
  for (int kt = 0; kt < NSTEP; ++kt) {
    const int cur = kt & 1, nxt = cur ^ 1;
    const unsigned short* kb = kv + cur * BUFS;
    unsigned short*       nb = kv + nxt * BUFS;
    const int ktp = (kt + 1 < NSTEP) ? (kt + 1) : kt;
    const int k0p = ktp * BK;

    // ---- prefetch next step (masks first: longest latency) ----
    i32x4 a0 = __builtin_nontemporal_load((const i32x4*)(amp + mgbase + k0p));
    i32x4 a1 = __builtin_nontemporal_load((const i32x4*)(amp + mgbase + k0p + 4));
    i32x4 g0 = __builtin_nontemporal_load((const i32x4*)(almp + mgbase + k0p));
    i32x4 g1 = __builtin_nontemporal_load((const i32x4*)(almp + mgbase + k0p + 4));
    bf16x8 k0l = *(const bf16x8*)(kgb + (k0p + kr_st) * FD + kc_st);
    bf16x8 k1l = *(const bf16x8*)(kgb + (k0p + kr_st) * FD + kc_st + 8);
    bf16x8 v0l = *(const bf16x8*)(vgb + ktp * (32 * FD) + t * 16);
    bf16x8 v1l = *(const bf16x8*)(vgb + ktp * (32 * FD) + t * 16 + 8);
    #pragma unroll
    for (int s = 0; s < 2; ++s) {
      float2 c2 = *(const float2*)(ckp + ((long long)(b * KL + k0p + s * 16 + l15)) * 2);
      ckx_b[nxt][s] = c2.x; cky_b[nxt][s] = c2.y;
    }

    // ---- QK^T over F=128 ----
    f32x4 S0 = (f32x4){0.f, 0.f, 0.f, 0.f};
    f32x4 S1 = (f32x4){0.f, 0.f, 0.f, 0.f};
    #pragma unroll
    for (int fs = 0; fs < 4; ++fs) {
      bf16x8 kb0 = *(const bf16x8*)&kb[(l15)      * KSTR + fs * 32 + q4 * 8];
      bf16x8 kb1 = *(const bf16x8*)&kb[(16 + l15) * KSTR + fs * 32 + q4 * 8];
      S0 = __builtin_amdgcn_mfma_f32_16x16x32_bf16(qfrag[fs], kb0, S0, 0, 0, 0);
      S1 = __builtin_amdgcn_mfma_f32_16x16x32_bf16(qfrag[fs], kb1, S1, 0, 0, 0);
    }

    // ---- transform: masks from packed LDS bytes ----
    #pragma unroll
    for (int s = 0; s < 2; ++s) {
      const f32x4 Sv = s ? S1 : S0;
      #pragma unroll
      for (int r = 0; r < 4; ++r) {
        unsigned char m = mlds[cur][(w * 16 + q4 * 4 + r) * MSTR + s * 16 + l15];
        float e = __builtin_amdgcn_exp2f(Sv[r] * sl2);
        lsum[r] += e;
        float dx = cqx[r] - ckx_b[cur][s], dy = cqy[r] - cky_b[cur][s];
        float d  = sqrtf(fmaf(dx, dx, dy * dy)) * bscale;
        float wv = (m & 1) ? 0.f : e;
        float tv = m ? 0.f : d;
        const int mm = q4 * 4 + r, c = s * 16 + l15;
        plds[w][0][mm * PSTR + c] = f2b(wv);
        plds[w][1][mm * PSTR + c] = f2b(tv);
      }
    }

    // ---- PV ----
    bf16x8 aw = *(const bf16x8*)&plds[w][0][l15 * PSTR + q4 * 8];
    bf16x8 at = *(const bf16x8*)&plds[w][1][l15 * PSTR + q4 * 8];
    #pragma unroll
    for (int n = 0; n < 8; ++n) {
      bf16x8 vb = *(const bf16x8*)&kb[VTOFF + (n * 16 + l15) * VTSTR + q4 * 8];
      O1[n] = __builtin_amdgcn_mfma_f32_16x16x32_bf16(aw, vb, O1[n], 0, 0, 0);
      O2[n] = __builtin_amdgcn_mfma_f32_16x16x32_bf16(at, vb, O2[n], 0, 0, 0);
    }

    // ---- stage next tile, single barrier ----
    unsigned ua = (unsigned)(a0[0] | (a0[1] << 8) | (a0[2] << 16) | (a0[3] << 24));
    unsigned ul = (unsigned)(g0[0] | (g0[1] << 8) | (g0[2] << 16) | (g0[3] << 24));
    *(unsigned*)&mlds[nxt][mlo] = ua | (ul << 1);
    ua = (unsigned)(a1[0] | (a1[1] << 8) | (a1[2] << 16) | (a1[3] << 24));
    ul = (unsigned)(g1[0] | (g1[1] << 8) | (g1[2] << 16) | (g1[3] << 24));
    *(unsigned*)&mlds[nxt][mlo + 4] = ua | (ul << 1);
    *(bf16x8*)&nb[kr_st * KSTR + kc_st]     = k0l;
    *(bf16x8*)&nb[kr_st * KSTR + kc_st + 8] = k1l;
    *(bf16x8*)&nb[VTOFF + vf_st * VTSTR + vh_st]     = v0l;
    *(bf16x8*)&nb[VTOFF + vf_st * VTSTR + vh_st + 8] = v1l;
    __syncthreads();
  }

  // ---- epilogue ----
  #pragma unroll
  for (int off = 1; off < 16; off <<= 1) {
    #pragma unroll
    for (int r = 0; r < 4; ++r) lsum[r] += __shfl_xor(lsum[r], off, 64);
  }
  float linv[4];
  #pragma unroll
  for (int r = 0; r < 4; ++r) linv[r] = 1.0f / lsum[r];

  #pragma unroll
  for (int n = 0; n < 8; ++n) {
    #pragma unroll
    for (int r = 0; r < 4; ++r) {
      const int qg_ = qbase + w * 16 + q4 * 4 + r;
      const int f   = n * 16 + l15;
      float val = O1[n][r] * linv[r] - O2[n][r];
      __builtin_nontemporal_store(val, outp + ((long long)(b * QL + qg_)) * FD + f);
    }
  }
}

extern "C" void kernel_launch(void* const* d_in, const int* in_sizes, int n_in,
                              void* d_out, int out_size, void* d_ws, size_t ws_size,
                              hipStream_t stream) {
  const float* q   = (const float*)d_in[0];
  const float* k   = (const float*)d_in[1];
  const float* v   = (const float*)d_in[2];
  const float* cq  = (const float*)d_in[3];
  const float* ck  = (const float*)d_in[4];
  const int*   am  = (const int*)d_in[5];
  const int*   alm = (const int*)d_in[6];
  const float* bs  = (const float*)d_in[7];
  const float* rm  = (const float*)d_in[8];
  float*       out = (float*)d_out;

  unsigned short* kb = (unsigned short*)d_ws;            // 8 MB bf16 K
  unsigned short* vt = kb + WS_HALF;                     // 8 MB bf16 V^T tiles

  hipLaunchKernelGGL(conv_k,  dim3(WS_HALF / 1024), dim3(256), 0, stream, k, kb);
  hipLaunchKernelGGL(conv_vt, dim3(B_ * 64),        dim3(256), 0, stream, v, vt);

  dim3 grid(B_ * (QL / BQ));   // 512 blocks, 2/CU
  dim3 block(256);
  hipLaunchKernelGGL(alibi_attn, grid, block, 0, stream,
                     kb, vt, q, cq, ck, am, alm, bs, rm, out);
}